// Round 3
// baseline (121.875 us; speedup 1.0000x reference)
//
#include <hip/hip_runtime.h>

// Problem constants (fixed by the reference):
//   B = 4194304 patches, each 2x2 f32  -> one float4 per patch
//   L = 5 affine-tanh layers, THRESHOLD = 0
#define B_TOTAL 4194304
#define NLAYER  5
#define NP      8      // patches per thread; grid 2048 = one full wave pass
#define BLOCK   256

#define LOG2E_F      1.442695040888963f
#define TWO_LOG2E_F  2.885390081777927f

// clang-native vector type: __builtin_nontemporal_load requires a real vector,
// not HIP's struct-based float4.
typedef float f32x4 __attribute__((ext_vector_type(4)));

// Fast reciprocal: single v_rcp_f32 (~1 ulp). rcp(inf)=0, so saturation limits stay exact.
__device__ __forceinline__ float fast_rcp(float x) { return __builtin_amdgcn_rcpf(x); }
// Raw v_exp_f32 (exp2). Saturates cleanly: exp2(+big)=inf, exp2(-big)=0.
__device__ __forceinline__ float fast_exp2(float x) { return __builtin_amdgcn_exp2f(x); }

// launch_bounds(256, 4): cap 128 VGPRs. The previous (256, 8) forced a 64-VGPR cap,
// which can't hold 8 in-flight float4 loads + temps without serializing/spilling.
__global__ __launch_bounds__(BLOCK, 4) void fraud_kernel(
    const f32x4* __restrict__ data,    // [B] patches as float4
    const float* __restrict__ Wc,      // [4]
    const float* __restrict__ bc,      // [1]
    const float* __restrict__ Wl,      // [L*4]
    const float* __restrict__ bl,      // [L*2]
    const float* __restrict__ scale,   // [L*2]
    const float* __restrict__ shift,   // [L*2]
    const float* __restrict__ Wf,      // [2]
    const float* __restrict__ bf,      // [1]
    float*       __restrict__ out)     // [B]
{
    // ---- Weights: wave-uniform loads, prescaled once per thread ----
    // sigmoid(z) = rcp(1 + exp2(-log2e * z))  -> fold -log2e into conv weights
    const f32x4 wc = *(const f32x4*)Wc;
    const float wc0 = wc.x * -LOG2E_F, wc1 = wc.y * -LOG2E_F,
                wc2 = wc.z * -LOG2E_F, wc3 = wc.w * -LOG2E_F;
    const float bc0 = bc[0] * -LOG2E_F;

    // tanh(z) = 1 - 2*rcp(exp2(2*log2e*z) + 1)
    // y = tanh(z)*sc + sh == fma(r, -2*sc, sc+sh) with r = rcp(exp2(z2)+1)
    float w0[NLAYER], w1[NLAYER], w2_[NLAYER], w3[NLAYER];
    float bb0[NLAYER], bb1[NLAYER];
    float m0[NLAYER], m1[NLAYER], a0[NLAYER], a1[NLAYER];
#pragma unroll
    for (int l = 0; l < NLAYER; ++l) {
        f32x4 wl = *(const f32x4*)(Wl + 4 * l);
        w0[l]  = wl.x * TWO_LOG2E_F; w1[l] = wl.y * TWO_LOG2E_F;
        w2_[l] = wl.z * TWO_LOG2E_F; w3[l] = wl.w * TWO_LOG2E_F;
        float2 b2 = *(const float2*)(bl + 2 * l);
        bb0[l] = b2.x * TWO_LOG2E_F; bb1[l] = b2.y * TWO_LOG2E_F;
        float2 s2 = *(const float2*)(scale + 2 * l);
        float2 h2 = *(const float2*)(shift + 2 * l);
        m0[l] = -2.0f * s2.x; m1[l] = -2.0f * s2.y;
        a0[l] = s2.x + h2.x;  a1[l] = s2.y + h2.y;
    }
    const float2 wf = *(const float2*)Wf;
    const float  bfv = bf[0];

    const int tid    = blockIdx.x * BLOCK + threadIdx.x;
    const int stride = gridDim.x * BLOCK;   // 524288

    // ---- Front-load all 8 streaming reads: 8 outstanding loads per wave ----
    f32x4 d[NP];
#pragma unroll
    for (int k = 0; k < NP; ++k)
        d[k] = __builtin_nontemporal_load(&data[tid + k * stride]);

#pragma unroll
    for (int k = 0; k < NP; ++k) {
        // Conv2d(1,1,2) on 2x2 patch == dot4 + bias (prescaled), then sigmoid
        float zn = fmaf(d[k].x, wc0,
                   fmaf(d[k].y, wc1,
                   fmaf(d[k].z, wc2,
                   fmaf(d[k].w, wc3, bc0))));
        float x0 = fast_rcp(1.0f + fast_exp2(zn));
        float x1 = 0.0f;   // folded away for l=0 by the unroller

#pragma unroll
        for (int l = 0; l < NLAYER; ++l) {
            float r0 = fast_rcp(fast_exp2(fmaf(x0, w0[l],  fmaf(x1, w1[l], bb0[l]))) + 1.0f);
            float r1 = fast_rcp(fast_exp2(fmaf(x0, w2_[l], fmaf(x1, w3[l], bb1[l]))) + 1.0f);
            x0 = fmaf(r0, m0[l], a0[l]);
            x1 = fmaf(r1, m1[l], a1[l]);
        }

        float res = fmaf(x0, wf.x, fmaf(x1, wf.y, bfv));
        __builtin_nontemporal_store(res, &out[tid + k * stride]);
    }
}

extern "C" void kernel_launch(void* const* d_in, const int* in_sizes, int n_in,
                              void* d_out, int out_size, void* d_ws, size_t ws_size,
                              hipStream_t stream) {
    const f32x4* data  = (const f32x4*)d_in[0];
    const float* Wc    = (const float*)d_in[1];
    const float* bc    = (const float*)d_in[2];
    const float* Wl    = (const float*)d_in[3];
    const float* bl    = (const float*)d_in[4];
    const float* scale = (const float*)d_in[5];
    const float* shift = (const float*)d_in[6];
    const float* Wf    = (const float*)d_in[7];
    const float* bf    = (const float*)d_in[8];
    float* out = (float*)d_out;

    const int grid = B_TOTAL / (BLOCK * NP);   // 4194304 / 2048 = 2048 blocks
    fraud_kernel<<<grid, BLOCK, 0, stream>>>(data, Wc, bc, Wl, bl, scale, shift, Wf, bf, out);
}

// Round 4
// 114.530 us; speedup vs baseline: 1.0641x; 1.0641x over previous
//
#include <hip/hip_runtime.h>

// Problem constants (fixed by the reference):
//   B = 4194304 patches, each 2x2 f32  -> one float4 per patch
//   L = 5 affine-tanh layers, THRESHOLD = 0
#define B_TOTAL 4194304
#define NLAYER  5
#define NP      8      // patches per thread; grid 2048 -> 8 blocks/CU, one full pass
#define BLOCK   256

#define LOG2E_F      1.442695040888963f
#define TWO_LOG2E_F  2.885390081777927f

// Fast reciprocal: single v_rcp_f32 (~1 ulp). rcp(inf)=0, so saturation limits stay exact.
__device__ __forceinline__ float fast_rcp(float x) { return __builtin_amdgcn_rcpf(x); }
// Raw v_exp_f32 (exp2). Saturates cleanly: exp2(+big)=inf, exp2(-big)=0.
__device__ __forceinline__ float fast_exp2(float x) { return __builtin_amdgcn_exp2f(x); }

// (256, 8): 64-VGPR cap -> 8 waves/SIMD; grid 2048 = 8 blocks/CU = ONE full-occupancy
// pass. Round-3 post-mortem: (256,4) halved residency -> two sequential passes,
// +5.4 us. TLP (32 waves/CU) hides streaming latency; ILP front-loading not needed.
__global__ __launch_bounds__(BLOCK, 8) void fraud_kernel(
    const float4* __restrict__ data,   // [B] patches as float4
    const float*  __restrict__ Wc,     // [4]
    const float*  __restrict__ bc,     // [1]
    const float*  __restrict__ Wl,     // [L*4]
    const float*  __restrict__ bl,     // [L*2]
    const float*  __restrict__ scale,  // [L*2]
    const float*  __restrict__ shift,  // [L*2]
    const float*  __restrict__ Wf,     // [2]
    const float*  __restrict__ bf,     // [1]
    float*        __restrict__ out)    // [B]
{
    // ---- Weights: wave-uniform loads, prescaled once per thread ----
    // sigmoid(z) = rcp(1 + exp2(-log2e * z))  -> fold -log2e into conv weights
    const float4 wc = *(const float4*)Wc;
    const float wc0 = wc.x * -LOG2E_F, wc1 = wc.y * -LOG2E_F,
                wc2 = wc.z * -LOG2E_F, wc3 = wc.w * -LOG2E_F;
    const float bc0 = bc[0] * -LOG2E_F;

    // tanh(z) = 1 - 2*rcp(exp2(2*log2e*z) + 1)
    // y = tanh(z)*sc + sh == fma(r, -2*sc, sc+sh) with r = rcp(exp2(z2)+1)
    float w0[NLAYER], w1[NLAYER], w2_[NLAYER], w3[NLAYER];
    float bb0[NLAYER], bb1[NLAYER];
    float m0[NLAYER], m1[NLAYER], a0[NLAYER], a1[NLAYER];
#pragma unroll
    for (int l = 0; l < NLAYER; ++l) {
        float4 wl = *(const float4*)(Wl + 4 * l);
        w0[l]  = wl.x * TWO_LOG2E_F; w1[l] = wl.y * TWO_LOG2E_F;
        w2_[l] = wl.z * TWO_LOG2E_F; w3[l] = wl.w * TWO_LOG2E_F;
        float2 b2 = *(const float2*)(bl + 2 * l);
        bb0[l] = b2.x * TWO_LOG2E_F; bb1[l] = b2.y * TWO_LOG2E_F;
        float2 s2 = *(const float2*)(scale + 2 * l);
        float2 h2 = *(const float2*)(shift + 2 * l);
        m0[l] = -2.0f * s2.x; m1[l] = -2.0f * s2.y;
        a0[l] = s2.x + h2.x;  a1[l] = s2.y + h2.y;
    }
    const float2 wf = *(const float2*)Wf;
    const float  bfv = bf[0];

    const int tid    = blockIdx.x * BLOCK + threadIdx.x;
    const int stride = gridDim.x * BLOCK;   // 524288

#pragma unroll
    for (int k = 0; k < NP; ++k) {
        const int i = tid + k * stride;    // coalesced across the wave
        const float4 d = data[i];

        // Conv2d(1,1,2) on 2x2 patch == dot4 + bias (prescaled), then sigmoid
        float zn = fmaf(d.x, wc0,
                   fmaf(d.y, wc1,
                   fmaf(d.z, wc2,
                   fmaf(d.w, wc3, bc0))));
        float x0 = fast_rcp(1.0f + fast_exp2(zn));
        float x1 = 0.0f;   // folded away for l=0 by the unroller

#pragma unroll
        for (int l = 0; l < NLAYER; ++l) {
            float r0 = fast_rcp(fast_exp2(fmaf(x0, w0[l],  fmaf(x1, w1[l], bb0[l]))) + 1.0f);
            float r1 = fast_rcp(fast_exp2(fmaf(x0, w2_[l], fmaf(x1, w3[l], bb1[l]))) + 1.0f);
            x0 = fmaf(r0, m0[l], a0[l]);
            x1 = fmaf(r1, m1[l], a1[l]);
        }

        out[i] = fmaf(x0, wf.x, fmaf(x1, wf.y, bfv));
    }
}

extern "C" void kernel_launch(void* const* d_in, const int* in_sizes, int n_in,
                              void* d_out, int out_size, void* d_ws, size_t ws_size,
                              hipStream_t stream) {
    const float4* data  = (const float4*)d_in[0];
    const float*  Wc    = (const float*)d_in[1];
    const float*  bc    = (const float*)d_in[2];
    const float*  Wl    = (const float*)d_in[3];
    const float*  bl    = (const float*)d_in[4];
    const float*  scale = (const float*)d_in[5];
    const float*  shift = (const float*)d_in[6];
    const float*  Wf    = (const float*)d_in[7];
    const float*  bf    = (const float*)d_in[8];
    float* out = (float*)d_out;

    const int grid = B_TOTAL / (BLOCK * NP);   // 4194304 / 2048 = 2048 blocks
    fraud_kernel<<<grid, BLOCK, 0, stream>>>(data, Wc, bc, Wl, bl, scale, shift, Wf, bf, out);
}